// Round 1
// baseline (1008.490 us; speedup 1.0000x reference)
//
#include <hip/hip_runtime.h>
#include <hip/hip_fp16.h>
#include <cstdint>
#include <cstddef>

typedef _Float16 half8 __attribute__((ext_vector_type(8)));
typedef _Float16 half4 __attribute__((ext_vector_type(4)));
typedef float floatx4 __attribute__((ext_vector_type(4)));

#define N_TOK 8192
#define DIM   1024

// epilogue modes
#define EPI_F32      0   // C fp32 = acc                      (S = q k^T)
#define EPI_BIAS_F32 1   // C fp32 = acc + bias[col]          (q, k)
#define EPI_BIAS_VT  2   // vt[col*ldvt+row] = h(acc+bias)    (v, transposed fp16)
#define EPI_SCALE    3   // C fp32 = acc * inv_l[row]         (out = P V)

// NT GEMM: C[m][n] = sum_k A[m][k] * B[n][k]
// SPLIT=true : A,B are fp32; A is staged as hi+lo fp16 (2-term compensated), B rounded to fp16.
// SPLIT=false: A,B are fp16 already.
template<int BM, int BN, bool SPLIT, int EPI>
__global__ __launch_bounds__(256)
void gemm_nt(const void* __restrict__ Ap, const void* __restrict__ Bp,
             int K, int lda, int ldb,
             void* __restrict__ Cp, int ldc,
             const float* __restrict__ bias,
             const float* __restrict__ inv_l,
             _Float16* __restrict__ vt, int ldvt)
{
    constexpr int LS = 48;                    // LDS row stride (halves): 32 data + 16 pad, 96B (16B-aligned)
    constexpr int MI = BM / 32;               // 16-tiles per wave in M   (wave tile = BM/2 x BN/2, 2x2 waves)
    constexpr int NI = BN / 32;
    constexpr int SMEM_ELTS = (SPLIT ? 2 : 1) * BM * LS + BN * LS;
    __shared__ _Float16 smem[SMEM_ELTS];
    _Float16* lA  = smem;
    _Float16* lAl = smem + BM * LS;                       // only used when SPLIT
    _Float16* lB  = smem + (SPLIT ? 2 : 1) * BM * LS;

    const int tid  = threadIdx.x;
    const int row0 = blockIdx.y * BM;
    const int col0 = blockIdx.x * BN;
    const int lane = tid & 63;
    const int w    = tid >> 6;
    const int wm   = w & 1, wn = w >> 1;
    const int quad = lane >> 4, lr = lane & 15;

    floatx4 acc[MI][NI];
    const floatx4 zero = {0.f, 0.f, 0.f, 0.f};
#pragma unroll
    for (int mi = 0; mi < MI; mi++)
#pragma unroll
        for (int ni = 0; ni < NI; ni++) acc[mi][ni] = zero;

    for (int k0 = 0; k0 < K; k0 += 32) {
        __syncthreads();
        if constexpr (SPLIT) {
            const float* Af = (const float*)Ap;
            const float* Bf = (const float*)Bp;
#pragma unroll
            for (int s = 0; s < BM / 32; s++) {
                int r = s * 32 + (tid >> 3), c = (tid & 7) * 4;
                float4 a = *(const float4*)(Af + (size_t)(row0 + r) * lda + k0 + c);
                half4 hh, hl;
                hh[0] = (_Float16)a.x; hl[0] = (_Float16)(a.x - (float)hh[0]);
                hh[1] = (_Float16)a.y; hl[1] = (_Float16)(a.y - (float)hh[1]);
                hh[2] = (_Float16)a.z; hl[2] = (_Float16)(a.z - (float)hh[2]);
                hh[3] = (_Float16)a.w; hl[3] = (_Float16)(a.w - (float)hh[3]);
                *(half4*)&lA [r * LS + c] = hh;
                *(half4*)&lAl[r * LS + c] = hl;
            }
#pragma unroll
            for (int s = 0; s < BN / 32; s++) {
                int r = s * 32 + (tid >> 3), c = (tid & 7) * 4;
                float4 b = *(const float4*)(Bf + (size_t)(col0 + r) * ldb + k0 + c);
                half4 hh;
                hh[0] = (_Float16)b.x; hh[1] = (_Float16)b.y;
                hh[2] = (_Float16)b.z; hh[3] = (_Float16)b.w;
                *(half4*)&lB[r * LS + c] = hh;
            }
        } else {
            const _Float16* Af = (const _Float16*)Ap;
            const _Float16* Bf = (const _Float16*)Bp;
#pragma unroll
            for (int s = 0; s < BM / 64; s++) {
                int r = s * 64 + (tid >> 2), c = (tid & 3) * 8;
                *(half8*)&lA[r * LS + c] = *(const half8*)(Af + (size_t)(row0 + r) * lda + k0 + c);
            }
#pragma unroll
            for (int s = 0; s < BN / 64; s++) {
                int r = s * 64 + (tid >> 2), c = (tid & 3) * 8;
                *(half8*)&lB[r * LS + c] = *(const half8*)(Bf + (size_t)(col0 + r) * ldb + k0 + c);
            }
        }
        __syncthreads();

        half8 af[MI], bf[NI];
        half8 alf[SPLIT ? MI : 1];
#pragma unroll
        for (int mi = 0; mi < MI; mi++) {
            af[mi] = *(half8*)&lA[(wm * (BM / 2) + mi * 16 + lr) * LS + quad * 8];
            if constexpr (SPLIT)
                alf[mi] = *(half8*)&lAl[(wm * (BM / 2) + mi * 16 + lr) * LS + quad * 8];
        }
#pragma unroll
        for (int ni = 0; ni < NI; ni++)
            bf[ni] = *(half8*)&lB[(wn * (BN / 2) + ni * 16 + lr) * LS + quad * 8];

#pragma unroll
        for (int mi = 0; mi < MI; mi++)
#pragma unroll
            for (int ni = 0; ni < NI; ni++) {
                acc[mi][ni] = __builtin_amdgcn_mfma_f32_16x16x32_f16(af[mi], bf[ni], acc[mi][ni], 0, 0, 0);
                if constexpr (SPLIT)
                    acc[mi][ni] = __builtin_amdgcn_mfma_f32_16x16x32_f16(alf[mi], bf[ni], acc[mi][ni], 0, 0, 0);
            }
    }

    // epilogue. C/D layout (verified m89/m91): D[row = quad*4 + r][col = lane&15]
#pragma unroll
    for (int mi = 0; mi < MI; mi++) {
#pragma unroll
        for (int ni = 0; ni < NI; ni++) {
            const int colg = col0 + wn * (BN / 2) + ni * 16 + lr;
            const int rowb = row0 + wm * (BM / 2) + mi * 16 + quad * 4;
            float bv = 0.f;
            if constexpr (EPI == EPI_BIAS_F32 || EPI == EPI_BIAS_VT) bv = bias[colg];
            if constexpr (EPI == EPI_BIAS_VT) {
                half4 hv;
#pragma unroll
                for (int r2 = 0; r2 < 4; r2++) hv[r2] = (_Float16)(acc[mi][ni][r2] + bv);
                *(half4*)&vt[(size_t)colg * ldvt + rowb] = hv;   // rowb % 4 == 0 -> 8B aligned
            } else {
#pragma unroll
                for (int r2 = 0; r2 < 4; r2++) {
                    const int rowg = rowb + r2;
                    const float v = acc[mi][ni][r2];
                    if constexpr (EPI == EPI_F32)
                        ((float*)Cp)[(size_t)rowg * ldc + colg] = v;
                    else if constexpr (EPI == EPI_BIAS_F32)
                        ((float*)Cp)[(size_t)rowg * ldc + colg] = v + bv;
                    else if constexpr (EPI == EPI_SCALE)
                        ((float*)Cp)[(size_t)rowg * ldc + colg] = v * inv_l[rowg];
                }
            }
        }
    }
}

// One block per row: load 8192-float score row to LDS, rowmax, write P = exp(s-m) fp16
// IN PLACE over the fp32 row (first 16KB of the 32KB row slot), and inv_l[row] = 1/sum.
__global__ __launch_bounds__(256)
void softmax_rows(float* __restrict__ S, float* __restrict__ inv_l)
{
    __shared__ float srow[N_TOK];
    __shared__ float red[4];
    const int tid = threadIdx.x;
    float* row = S + (size_t)blockIdx.x * N_TOK;

    float mx = -3.0e38f;
#pragma unroll
    for (int i = 0; i < 8; i++) {
        const int v = i * 256 + tid;
        const float4 f = ((const float4*)row)[v];
        ((float4*)srow)[v] = f;
        mx = fmaxf(mx, fmaxf(fmaxf(f.x, f.y), fmaxf(f.z, f.w)));
    }
#pragma unroll
    for (int off = 32; off > 0; off >>= 1) mx = fmaxf(mx, __shfl_down(mx, off));
    if ((tid & 63) == 0) red[tid >> 6] = mx;
    __syncthreads();
    mx = fmaxf(fmaxf(red[0], red[1]), fmaxf(red[2], red[3]));
    __syncthreads();                      // before reusing red[] for sums

    float sum = 0.f;
    _Float16* prow = (_Float16*)row;      // in-place fp16 P over the fp32 S row
#pragma unroll
    for (int i = 0; i < 8; i++) {
        const int v = i * 256 + tid;
        const float4 f = ((const float4*)srow)[v];
        const float e0 = __expf(f.x - mx), e1 = __expf(f.y - mx);
        const float e2 = __expf(f.z - mx), e3 = __expf(f.w - mx);
        sum += (e0 + e1) + (e2 + e3);
        half4 h; h[0] = (_Float16)e0; h[1] = (_Float16)e1; h[2] = (_Float16)e2; h[3] = (_Float16)e3;
        ((half4*)prow)[v] = h;
    }
#pragma unroll
    for (int off = 32; off > 0; off >>= 1) sum += __shfl_down(sum, off);
    if ((tid & 63) == 0) red[tid >> 6] = sum;
    __syncthreads();
    if (tid == 0) inv_l[blockIdx.x] = 1.f / (red[0] + red[1] + red[2] + red[3]);
}

extern "C" void kernel_launch(void* const* d_in, const int* in_sizes, int n_in,
                              void* d_out, int out_size, void* d_ws, size_t ws_size,
                              hipStream_t stream)
{
    const float* E  = (const float*)d_in[0];
    const float* Wq = (const float*)d_in[1];
    const float* bq = (const float*)d_in[2];
    const float* Wk = (const float*)d_in[3];
    const float* bk = (const float*)d_in[4];
    const float* Wv = (const float*)d_in[5];
    const float* bv = (const float*)d_in[6];
    float* out = (float*)d_out;

    char* ws = (char*)d_ws;
    const size_t MB = 1024ull * 1024ull;
    float*    q    = (float*)(ws);                 // 32 MB  fp32 [N,D]
    float*    kmat = (float*)(ws + 32 * MB);       // 32 MB  fp32 [N,D]
    _Float16* vt   = (_Float16*)(ws + 64 * MB);    // 16 MB  fp16 [D,N] (v transposed)
    float*    invl = (float*)(ws + 80 * MB);       // 32 KB  fp32 [N]
    float*    Sc   = (float*)(ws + 80 * MB + 65536); // NC*8192 fp32 score chunk (P fp16 in place)
    const size_t fixed = 80 * MB + 65536;

    // pick the largest row-chunk that fits the workspace (ws_size is constant across calls)
    int NC = 128;
    const int cands[6] = {8192, 4096, 2048, 1024, 512, 256};
    for (int i = 0; i < 6; i++) {
        if (ws_size >= fixed + (size_t)cands[i] * N_TOK * 4) { NC = cands[i]; break; }
    }

    const dim3 blk(256, 1, 1);

    // ---- QKV projections: x @ W^T + b (NT GEMM, 2-term compensated fp16) ----
    gemm_nt<128, 128, true, EPI_BIAS_F32><<<dim3(DIM / 128, N_TOK / 128, 1), blk, 0, stream>>>(
        E, Wq, DIM, DIM, DIM, q, DIM, bq, nullptr, nullptr, 0);
    gemm_nt<128, 128, true, EPI_BIAS_F32><<<dim3(DIM / 128, N_TOK / 128, 1), blk, 0, stream>>>(
        E, Wk, DIM, DIM, DIM, kmat, DIM, bk, nullptr, nullptr, 0);
    gemm_nt<128, 128, true, EPI_BIAS_VT><<<dim3(DIM / 128, N_TOK / 128, 1), blk, 0, stream>>>(
        E, Wv, DIM, DIM, DIM, nullptr, 0, bv, nullptr, vt, N_TOK);

    // ---- chunked scores -> softmax -> PV ----
    const int nchunks = N_TOK / NC;
    for (int c = 0; c < nchunks; c++) {
        const float* qc = q + (size_t)c * NC * DIM;
        // S = q_c @ k^T  (fp32 into Sc)
        gemm_nt<128, 128, true, EPI_F32><<<dim3(N_TOK / 128, NC / 128, 1), blk, 0, stream>>>(
            qc, kmat, DIM, DIM, DIM, Sc, N_TOK, nullptr, nullptr, nullptr, 0);
        // rowwise softmax: P=exp(s-m) fp16 in place, invl=1/sum
        softmax_rows<<<dim3(NC, 1, 1), blk, 0, stream>>>(Sc, invl + (size_t)c * NC);
        // out_c = (P @ V) * invl   : A = P fp16 (row stride 2*N_TOK halves), B = vt [D,N]
        gemm_nt<128, 64, false, EPI_SCALE><<<dim3(DIM / 64, NC / 128, 1), blk, 0, stream>>>(
            (const void*)Sc, (const void*)vt, N_TOK, 2 * N_TOK, N_TOK,
            out + (size_t)c * NC * DIM, DIM, nullptr, invl + (size_t)c * NC, nullptr, 0);
    }
}

// Round 2
// 960.934 us; speedup vs baseline: 1.0495x; 1.0495x over previous
//
#include <hip/hip_runtime.h>
#include <hip/hip_fp16.h>
#include <cstdint>
#include <cstddef>

typedef _Float16 half8 __attribute__((ext_vector_type(8)));
typedef _Float16 half4 __attribute__((ext_vector_type(4)));
typedef float floatx4 __attribute__((ext_vector_type(4)));

#define N_TOK 8192
#define DIM   1024

// epilogue modes
#define EPI_F32   0   // C fp32 = acc                         (S = q k^T)
#define EPI_HILO  1   // C f16 = hi(acc+bias), C2 f16 = lo    (q)
#define EPI_HI    2   // C f16 = hi(acc+bias)                 (k)
#define EPI_VT    3   // C f16 at [colg*ldc+row] = acc+bias   (v transposed)
#define EPI_SCALE 4   // C fp32 = acc * invl[row]             (out = P V)

__device__ __forceinline__ void async_tile16(const _Float16* gp, _Float16* lp) {
    __builtin_amdgcn_global_load_lds(
        (const __attribute__((address_space(1))) void*)gp,
        (__attribute__((address_space(3))) void*)lp, 16, 0, 0);
}

// NT GEMM, all-fp16 inputs: C[m][n] = sum_k A[m][k]*B[n][k]  (+ optional lo-term of A)
// Staging: global_load_lds 16B/lane, XOR-swizzled chunk placement (j ^= r&3).
template<int BM, int BN, bool ASPLIT, int EPI>
__global__ __launch_bounds__(256)
void gemm_f16(const _Float16* __restrict__ Ahi, const _Float16* __restrict__ Alo,
              const _Float16* __restrict__ B,
              int K, int lda, int ldb,
              void* __restrict__ C, int ldc, void* __restrict__ C2,
              const float* __restrict__ bias, const float* __restrict__ invl)
{
    constexpr int MI = BM / 32;           // 2x2 waves, wave tile BM/2 x BN/2
    constexpr int NI = BN / 32;
    constexpr int A_ELTS = BM * 32;       // BK = 32 halves, no pad (global_load_lds)
    constexpr int B_ELTS = BN * 32;
    __shared__ _Float16 smem[(ASPLIT ? 2 : 1) * A_ELTS + B_ELTS];
    constexpr int tAhi = 0;
    constexpr int tAlo = A_ELTS;                        // if ASPLIT
    constexpr int tB   = (ASPLIT ? 2 : 1) * A_ELTS;

    const int tid  = threadIdx.x;
    const int row0 = blockIdx.y * BM;
    const int col0 = blockIdx.x * BN;
    const int lane = tid & 63;
    const int w    = tid >> 6;
    const int wm   = w & 1, wn = w >> 1;
    const int quad = lane >> 4, lr = lane & 15;
    const int jx   = (quad ^ (lr & 3)) * 8;             // swizzled chunk col for frag reads

    floatx4 acc[MI][NI];
    const floatx4 zero = {0.f, 0.f, 0.f, 0.f};
#pragma unroll
    for (int mi = 0; mi < MI; mi++)
#pragma unroll
        for (int ni = 0; ni < NI; ni++) acc[mi][ni] = zero;

    // staging: chunk c -> lds (r = c>>2, jl = c&3), global chunk jg = jl ^ (r&3)
    const int r_s  = tid >> 2;            // c = i*256 + tid : r = c>>2 advances by 64/iter
    const int jl_s = tid & 3;

    for (int k0 = 0; k0 < K; k0 += 32) {
        __syncthreads();
#pragma unroll
        for (int i = 0; i < BM / 64; i++) {
            const int r = i * 64 + r_s;
            const int jg = jl_s ^ (r & 3);
            async_tile16(Ahi + (size_t)(row0 + r) * lda + k0 + jg * 8,
                         smem + tAhi + (i * 256 + tid) * 8);
            if constexpr (ASPLIT)
                async_tile16(Alo + (size_t)(row0 + r) * lda + k0 + jg * 8,
                             smem + tAlo + (i * 256 + tid) * 8);
        }
#pragma unroll
        for (int i = 0; i < BN / 64; i++) {
            const int r = i * 64 + r_s;
            const int jg = jl_s ^ (r & 3);
            async_tile16(B + (size_t)(col0 + r) * ldb + k0 + jg * 8,
                         smem + tB + (i * 256 + tid) * 8);
        }
        __syncthreads();

        half8 af[MI], bf[NI];
        half8 al[ASPLIT ? MI : 1];
#pragma unroll
        for (int mi = 0; mi < MI; mi++) {
            const int r = wm * (BM / 2) + mi * 16 + lr;
            af[mi] = *(half8*)&smem[tAhi + r * 32 + jx];
            if constexpr (ASPLIT) al[mi] = *(half8*)&smem[tAlo + r * 32 + jx];
        }
#pragma unroll
        for (int ni = 0; ni < NI; ni++) {
            const int r = wn * (BN / 2) + ni * 16 + lr;
            bf[ni] = *(half8*)&smem[tB + r * 32 + jx];
        }

#pragma unroll
        for (int mi = 0; mi < MI; mi++)
#pragma unroll
            for (int ni = 0; ni < NI; ni++) {
                acc[mi][ni] = __builtin_amdgcn_mfma_f32_16x16x32_f16(af[mi], bf[ni], acc[mi][ni], 0, 0, 0);
                if constexpr (ASPLIT)
                    acc[mi][ni] = __builtin_amdgcn_mfma_f32_16x16x32_f16(al[mi], bf[ni], acc[mi][ni], 0, 0, 0);
            }
    }

    // epilogue. C/D layout (verified m89/m91): D[row = quad*4 + r2][col = lane&15]
#pragma unroll
    for (int mi = 0; mi < MI; mi++) {
#pragma unroll
        for (int ni = 0; ni < NI; ni++) {
            const int colg = col0 + wn * (BN / 2) + ni * 16 + lr;
            const int rowb = row0 + wm * (BM / 2) + mi * 16 + quad * 4;
            float bv = 0.f;
            if constexpr (EPI == EPI_HILO || EPI == EPI_HI || EPI == EPI_VT) bv = bias[colg];
            if constexpr (EPI == EPI_VT) {
                half4 hv;
#pragma unroll
                for (int r2 = 0; r2 < 4; r2++) hv[r2] = (_Float16)(acc[mi][ni][r2] + bv);
                *(half4*)&((_Float16*)C)[(size_t)colg * ldc + rowb] = hv;   // rowb%4==0 -> 8B aligned
            } else {
#pragma unroll
                for (int r2 = 0; r2 < 4; r2++) {
                    const int rowg = rowb + r2;
                    const float v = acc[mi][ni][r2];
                    if constexpr (EPI == EPI_F32) {
                        ((float*)C)[(size_t)rowg * ldc + colg] = v;
                    } else if constexpr (EPI == EPI_SCALE) {
                        ((float*)C)[(size_t)rowg * ldc + colg] = v * invl[rowg];
                    } else {  // EPI_HILO / EPI_HI
                        const float t = v + bv;
                        const _Float16 hi = (_Float16)t;
                        ((_Float16*)C)[(size_t)rowg * ldc + colg] = hi;
                        if constexpr (EPI == EPI_HILO)
                            ((_Float16*)C2)[(size_t)rowg * ldc + colg] = (_Float16)(t - (float)hi);
                    }
                }
            }
        }
    }
}

// fp32 -> fp16 hi (+lo) pre-split. grid.y = unit: 0..7 = E chunks, 8/9/10 = Wq/Wk/Wv (hi only).
__global__ __launch_bounds__(256)
void split_inputs(const float* __restrict__ E,
                  const float* __restrict__ Wq, const float* __restrict__ Wk, const float* __restrict__ Wv,
                  _Float16* __restrict__ Ehi, _Float16* __restrict__ Elo,
                  _Float16* __restrict__ Wqh, _Float16* __restrict__ Wkh, _Float16* __restrict__ Wvh)
{
    const int u = blockIdx.y;
    const size_t idx = ((size_t)blockIdx.x * 256 + threadIdx.x) * 4;   // float index within unit
    const size_t MM = (size_t)DIM * DIM;
    const float* src; _Float16* dhi; _Float16* dlo = nullptr;
    if (u < 8)      { src = E + u * MM;  dhi = Ehi + u * MM; dlo = Elo + u * MM; }
    else if (u == 8){ src = Wq; dhi = Wqh; }
    else if (u == 9){ src = Wk; dhi = Wkh; }
    else            { src = Wv; dhi = Wvh; }
    const float4 f = *(const float4*)(src + idx);
    half4 hh;
    hh[0] = (_Float16)f.x; hh[1] = (_Float16)f.y; hh[2] = (_Float16)f.z; hh[3] = (_Float16)f.w;
    *(half4*)(dhi + idx) = hh;
    if (u < 8) {
        half4 hl;
        hl[0] = (_Float16)(f.x - (float)hh[0]); hl[1] = (_Float16)(f.y - (float)hh[1]);
        hl[2] = (_Float16)(f.z - (float)hh[2]); hl[3] = (_Float16)(f.w - (float)hh[3]);
        *(half4*)(dlo + idx) = hl;
    }
}

// One block per row: rowmax, P = exp(s-m) fp16 IN PLACE over fp32 row, inv_l = 1/sum.
__global__ __launch_bounds__(256)
void softmax_rows(float* __restrict__ S, float* __restrict__ inv_l)
{
    __shared__ float srow[N_TOK];
    __shared__ float red[4];
    const int tid = threadIdx.x;
    float* row = S + (size_t)blockIdx.x * N_TOK;

    float mx = -3.0e38f;
#pragma unroll
    for (int i = 0; i < 8; i++) {
        const int v = i * 256 + tid;
        const float4 f = ((const float4*)row)[v];
        ((float4*)srow)[v] = f;
        mx = fmaxf(mx, fmaxf(fmaxf(f.x, f.y), fmaxf(f.z, f.w)));
    }
#pragma unroll
    for (int off = 32; off > 0; off >>= 1) mx = fmaxf(mx, __shfl_down(mx, off));
    if ((tid & 63) == 0) red[tid >> 6] = mx;
    __syncthreads();
    mx = fmaxf(fmaxf(red[0], red[1]), fmaxf(red[2], red[3]));
    __syncthreads();

    float sum = 0.f;
    _Float16* prow = (_Float16*)row;
#pragma unroll
    for (int i = 0; i < 8; i++) {
        const int v = i * 256 + tid;
        const float4 f = ((const float4*)srow)[v];
        const float e0 = __expf(f.x - mx), e1 = __expf(f.y - mx);
        const float e2 = __expf(f.z - mx), e3 = __expf(f.w - mx);
        sum += (e0 + e1) + (e2 + e3);
        half4 h; h[0] = (_Float16)e0; h[1] = (_Float16)e1; h[2] = (_Float16)e2; h[3] = (_Float16)e3;
        ((half4*)prow)[v] = h;
    }
#pragma unroll
    for (int off = 32; off > 0; off >>= 1) sum += __shfl_down(sum, off);
    if ((tid & 63) == 0) red[tid >> 6] = sum;
    __syncthreads();
    if (tid == 0) inv_l[blockIdx.x] = 1.f / (red[0] + red[1] + red[2] + red[3]);
}

extern "C" void kernel_launch(void* const* d_in, const int* in_sizes, int n_in,
                              void* d_out, int out_size, void* d_ws, size_t ws_size,
                              hipStream_t stream)
{
    const float* E  = (const float*)d_in[0];
    const float* Wq = (const float*)d_in[1];
    const float* bq = (const float*)d_in[2];
    const float* Wk = (const float*)d_in[3];
    const float* bk = (const float*)d_in[4];
    const float* Wv = (const float*)d_in[5];
    const float* bv = (const float*)d_in[6];
    float* out = (float*)d_out;

    char* ws = (char*)d_ws;
    const size_t SZ = (size_t)N_TOK * DIM * sizeof(_Float16);   // 16 MiB
    const size_t WW = (size_t)DIM * DIM * sizeof(_Float16);     // 2 MiB
    _Float16* q_hi = (_Float16*)(ws);
    _Float16* q_lo = (_Float16*)(ws + SZ);
    _Float16* k_hi = (_Float16*)(ws + 2 * SZ);
    _Float16* vt   = (_Float16*)(ws + 3 * SZ);
    float*    invl = (float*)(ws + 4 * SZ);
    char*     scratch = ws + 4 * SZ + 65536;
    // scratch holds E-split + W-rounded during QKV, then is reused as the score chunk Sc.
    _Float16* Ehi = (_Float16*)(scratch);
    _Float16* Elo = (_Float16*)(scratch + SZ);
    _Float16* Wqh = (_Float16*)(scratch + 2 * SZ);
    _Float16* Wkh = (_Float16*)(scratch + 2 * SZ + WW);
    _Float16* Wvh = (_Float16*)(scratch + 2 * SZ + 2 * WW);
    float*    Sc  = (float*)(scratch);
    const size_t esplit_bytes = 2 * SZ + 3 * WW;
    const size_t base = 4 * SZ + 65536;

    int NC = 256;
    const int cands[6] = {8192, 4096, 2048, 1024, 512, 256};
    for (int i = 0; i < 6; i++) {
        size_t sc = (size_t)cands[i] * N_TOK * 4;
        size_t need = base + (sc > esplit_bytes ? sc : esplit_bytes);
        if (ws_size >= need) { NC = cands[i]; break; }
    }

    const dim3 blk(256, 1, 1);

    // ---- pre-split: E -> hi/lo fp16, W -> hi fp16 ----
    split_inputs<<<dim3(DIM * DIM / 1024, 11, 1), blk, 0, stream>>>(
        E, Wq, Wk, Wv, Ehi, Elo, Wqh, Wkh, Wvh);

    // ---- QKV projections (pure fp16, A 2-term) ----
    gemm_f16<128, 128, true, EPI_HILO><<<dim3(DIM / 128, N_TOK / 128, 1), blk, 0, stream>>>(
        Ehi, Elo, Wqh, DIM, DIM, DIM, q_hi, DIM, q_lo, bq, nullptr);
    gemm_f16<128, 128, true, EPI_HI><<<dim3(DIM / 128, N_TOK / 128, 1), blk, 0, stream>>>(
        Ehi, Elo, Wkh, DIM, DIM, DIM, k_hi, DIM, nullptr, bk, nullptr);
    gemm_f16<128, 128, true, EPI_VT><<<dim3(DIM / 128, N_TOK / 128, 1), blk, 0, stream>>>(
        Ehi, Elo, Wvh, DIM, DIM, DIM, vt, N_TOK, nullptr, bv, nullptr);

    // ---- chunked scores -> softmax -> PV ----
    const int nchunks = N_TOK / NC;
    for (int c = 0; c < nchunks; c++) {
        const size_t roff = (size_t)c * NC;
        // S = q_c @ k^T  (fp32 into Sc), A split hi+lo
        gemm_f16<128, 128, true, EPI_F32><<<dim3(N_TOK / 128, NC / 128, 1), blk, 0, stream>>>(
            q_hi + roff * DIM, q_lo + roff * DIM, k_hi, DIM, DIM, DIM,
            Sc, N_TOK, nullptr, nullptr, nullptr);
        // rowwise softmax: P=exp(s-m) fp16 in place, invl=1/sum
        softmax_rows<<<dim3(NC, 1, 1), blk, 0, stream>>>(Sc, invl + roff);
        // out_c = (P @ V) * invl : A = P fp16 (row stride 2*N_TOK halves), B = vt [D,N]
        gemm_f16<128, 64, false, EPI_SCALE><<<dim3(DIM / 64, NC / 128, 1), blk, 0, stream>>>(
            (const _Float16*)Sc, nullptr, vt, N_TOK, 2 * N_TOK, N_TOK,
            out + roff * DIM, DIM, nullptr, nullptr, invl + roff);
    }
}

// Round 3
// 799.722 us; speedup vs baseline: 1.2611x; 1.2016x over previous
//
#include <hip/hip_runtime.h>
#include <hip/hip_fp16.h>
#include <cstdint>
#include <cstddef>

typedef _Float16 half8 __attribute__((ext_vector_type(8)));
typedef _Float16 half4 __attribute__((ext_vector_type(4)));
typedef float floatx4 __attribute__((ext_vector_type(4)));

#define N_TOK 8192
#define DIM   1024

// epilogue modes
#define EPI_F32   0   // C fp32 = acc                         (S = q k^T)
#define EPI_HILO  1   // C f16 = hi(acc+bias), C2 f16 = lo    (q)
#define EPI_HI    2   // C f16 = hi(acc+bias)                 (k)
#define EPI_VT    3   // C f16 at [colg*ldc+row] = acc+bias   (v transposed)
#define EPI_ATOM  4   // atomicAdd(C fp32, acc * invl[row])   (out = P V, split-K)

__device__ __forceinline__ void async_tile16(const _Float16* gp, _Float16* lp) {
    __builtin_amdgcn_global_load_lds(
        (const __attribute__((address_space(1))) void*)gp,
        (__attribute__((address_space(3))) void*)lp, 16, 0, 0);
}

// NT GEMM, fp16 inputs: C[m][n] = sum_k A[m][k]*B[n][k]  (+ optional lo-term of A)
// global_load_lds 16B staging, XOR-swizzled chunk placement, optional XCD remap,
// optional split-K over blockIdx.z (kslice = K per z).
template<int BM, int BN, int BK, bool ASPLIT, int EPI, bool REMAP>
__global__ __launch_bounds__(256)
void gemm_f16(const _Float16* __restrict__ Ahi, const _Float16* __restrict__ Alo,
              const _Float16* __restrict__ B,
              int kslice, int lda, int ldb,
              void* __restrict__ C, int ldc, void* __restrict__ C2,
              const float* __restrict__ bias, const float* __restrict__ invl)
{
    constexpr int MI = BM / 32;           // 2x2 waves, wave tile BM/2 x BN/2
    constexpr int NI = BN / 32;
    constexpr int CPR = BK / 8;           // 16B chunks per row
    constexpr int SW  = CPR - 1;          // swizzle mask
    constexpr int RPP = 2048 / BK;        // rows staged per 256-thread pass
    constexpr int IA  = BM * BK / 2048;   // A staging passes
    constexpr int IB  = BN * BK / 2048;
    constexpr int A_ELTS = BM * BK;
    constexpr int B_ELTS = BN * BK;
    __shared__ _Float16 smem[(ASPLIT ? 2 : 1) * A_ELTS + B_ELTS];
    constexpr int tAhi = 0;
    constexpr int tAlo = A_ELTS;
    constexpr int tB   = (ASPLIT ? 2 : 1) * A_ELTS;

    int bx = blockIdx.x, by = blockIdx.y, bz = blockIdx.z;
    if constexpr (REMAP) {
        const int gx = gridDim.x, gy = gridDim.y;
        const int gxy = gx * gy;
        const int nb = gxy * gridDim.z;
        const int bid = bz * gxy + by * gx + bx;
        const int nid = (bid & 7) * (nb >> 3) + (bid >> 3);
        bx = nid % gx; by = (nid / gx) % gy; bz = nid / gxy;
    }

    const int tid  = threadIdx.x;
    const int row0 = by * BM;
    const int col0 = bx * BN;
    const int lane = tid & 63;
    const int w    = tid >> 6;
    const int wm   = w & 1, wn = w >> 1;
    const int quad = lane >> 4, lr = lane & 15;

    floatx4 acc[MI][NI];
    const floatx4 zero = {0.f, 0.f, 0.f, 0.f};
#pragma unroll
    for (int mi = 0; mi < MI; mi++)
#pragma unroll
        for (int ni = 0; ni < NI; ni++) acc[mi][ni] = zero;

    const int r_s = tid / CPR;
    const int j_s = tid % CPR;

    const int k_beg = bz * kslice;
    for (int k0 = k_beg; k0 < k_beg + kslice; k0 += BK) {
        __syncthreads();
#pragma unroll
        for (int i = 0; i < IA; i++) {
            const int r = i * RPP + r_s;
            const int jg = j_s ^ (r & SW);
            async_tile16(Ahi + (size_t)(row0 + r) * lda + k0 + jg * 8,
                         smem + tAhi + (i * 256 + tid) * 8);
            if constexpr (ASPLIT)
                async_tile16(Alo + (size_t)(row0 + r) * lda + k0 + jg * 8,
                             smem + tAlo + (i * 256 + tid) * 8);
        }
#pragma unroll
        for (int i = 0; i < IB; i++) {
            const int r = i * RPP + r_s;
            const int jg = j_s ^ (r & SW);
            async_tile16(B + (size_t)(col0 + r) * ldb + k0 + jg * 8,
                         smem + tB + (i * 256 + tid) * 8);
        }
        __syncthreads();

#pragma unroll
        for (int kk = 0; kk < BK / 32; kk++) {
            half8 af[MI], bf[NI];
            half8 al[ASPLIT ? MI : 1];
#pragma unroll
            for (int mi = 0; mi < MI; mi++) {
                const int r = wm * (BM / 2) + mi * 16 + lr;
                const int cj = ((kk * 4 + quad) ^ (r & SW)) * 8;
                af[mi] = *(half8*)&smem[tAhi + r * BK + cj];
                if constexpr (ASPLIT) al[mi] = *(half8*)&smem[tAlo + r * BK + cj];
            }
#pragma unroll
            for (int ni = 0; ni < NI; ni++) {
                const int r = wn * (BN / 2) + ni * 16 + lr;
                const int cj = ((kk * 4 + quad) ^ (r & SW)) * 8;
                bf[ni] = *(half8*)&smem[tB + r * BK + cj];
            }
#pragma unroll
            for (int mi = 0; mi < MI; mi++)
#pragma unroll
                for (int ni = 0; ni < NI; ni++) {
                    acc[mi][ni] = __builtin_amdgcn_mfma_f32_16x16x32_f16(af[mi], bf[ni], acc[mi][ni], 0, 0, 0);
                    if constexpr (ASPLIT)
                        acc[mi][ni] = __builtin_amdgcn_mfma_f32_16x16x32_f16(al[mi], bf[ni], acc[mi][ni], 0, 0, 0);
                }
        }
    }

    // epilogue. C/D layout (verified m89/m91): D[row = quad*4 + r2][col = lane&15]
#pragma unroll
    for (int mi = 0; mi < MI; mi++) {
#pragma unroll
        for (int ni = 0; ni < NI; ni++) {
            const int colg = col0 + wn * (BN / 2) + ni * 16 + lr;
            const int rowb = row0 + wm * (BM / 2) + mi * 16 + quad * 4;
            float bv = 0.f;
            if constexpr (EPI == EPI_HILO || EPI == EPI_HI || EPI == EPI_VT) bv = bias[colg];
            if constexpr (EPI == EPI_VT) {
                half4 hv;
#pragma unroll
                for (int r2 = 0; r2 < 4; r2++) hv[r2] = (_Float16)(acc[mi][ni][r2] + bv);
                *(half4*)&((_Float16*)C)[(size_t)colg * ldc + rowb] = hv;   // rowb%4==0 -> 8B aligned
            } else {
#pragma unroll
                for (int r2 = 0; r2 < 4; r2++) {
                    const int rowg = rowb + r2;
                    const float v = acc[mi][ni][r2];
                    if constexpr (EPI == EPI_F32) {
                        ((float*)C)[(size_t)rowg * ldc + colg] = v;
                    } else if constexpr (EPI == EPI_ATOM) {
                        atomicAdd(&((float*)C)[(size_t)rowg * ldc + colg], v * invl[rowg]);
                    } else {  // EPI_HILO / EPI_HI
                        const float t = v + bv;
                        const _Float16 hi = (_Float16)t;
                        ((_Float16*)C)[(size_t)rowg * ldc + colg] = hi;
                        if constexpr (EPI == EPI_HILO)
                            ((_Float16*)C2)[(size_t)rowg * ldc + colg] = (_Float16)(t - (float)hi);
                    }
                }
            }
        }
    }
}

__global__ __launch_bounds__(256)
void zero_f32(float* __restrict__ p)
{
    const size_t i = ((size_t)blockIdx.x * 256 + threadIdx.x) * 4;
    const float4 z = {0.f, 0.f, 0.f, 0.f};
    *(float4*)(p + i) = z;
}

// fp32 -> fp16 hi (+lo) pre-split. grid.y = unit: 0..7 = E chunks, 8/9/10 = Wq/Wk/Wv (hi only).
__global__ __launch_bounds__(256)
void split_inputs(const float* __restrict__ E,
                  const float* __restrict__ Wq, const float* __restrict__ Wk, const float* __restrict__ Wv,
                  _Float16* __restrict__ Ehi, _Float16* __restrict__ Elo,
                  _Float16* __restrict__ Wqh, _Float16* __restrict__ Wkh, _Float16* __restrict__ Wvh)
{
    const int u = blockIdx.y;
    const size_t idx = ((size_t)blockIdx.x * 256 + threadIdx.x) * 4;
    const size_t MM = (size_t)DIM * DIM;
    const float* src; _Float16* dhi; _Float16* dlo = nullptr;
    if (u < 8)      { src = E + u * MM;  dhi = Ehi + u * MM; dlo = Elo + u * MM; }
    else if (u == 8){ src = Wq; dhi = Wqh; }
    else if (u == 9){ src = Wk; dhi = Wkh; }
    else            { src = Wv; dhi = Wvh; }
    const float4 f = *(const float4*)(src + idx);
    half4 hh;
    hh[0] = (_Float16)f.x; hh[1] = (_Float16)f.y; hh[2] = (_Float16)f.z; hh[3] = (_Float16)f.w;
    *(half4*)(dhi + idx) = hh;
    if (u < 8) {
        half4 hl;
        hl[0] = (_Float16)(f.x - (float)hh[0]); hl[1] = (_Float16)(f.y - (float)hh[1]);
        hl[2] = (_Float16)(f.z - (float)hh[2]); hl[3] = (_Float16)(f.w - (float)hh[3]);
        *(half4*)(dlo + idx) = hl;
    }
}

// One block per row: rowmax, P = exp(s-m) fp16 IN PLACE over fp32 row, inv_l = 1/sum.
__global__ __launch_bounds__(256)
void softmax_rows(float* __restrict__ S, float* __restrict__ inv_l)
{
    __shared__ float srow[N_TOK];
    __shared__ float red[4];
    const int tid = threadIdx.x;
    float* row = S + (size_t)blockIdx.x * N_TOK;

    float mx = -3.0e38f;
#pragma unroll
    for (int i = 0; i < 8; i++) {
        const int v = i * 256 + tid;
        const float4 f = ((const float4*)row)[v];
        ((float4*)srow)[v] = f;
        mx = fmaxf(mx, fmaxf(fmaxf(f.x, f.y), fmaxf(f.z, f.w)));
    }
#pragma unroll
    for (int off = 32; off > 0; off >>= 1) mx = fmaxf(mx, __shfl_down(mx, off));
    if ((tid & 63) == 0) red[tid >> 6] = mx;
    __syncthreads();
    mx = fmaxf(fmaxf(red[0], red[1]), fmaxf(red[2], red[3]));
    __syncthreads();

    float sum = 0.f;
    _Float16* prow = (_Float16*)row;
#pragma unroll
    for (int i = 0; i < 8; i++) {
        const int v = i * 256 + tid;
        const float4 f = ((const float4*)srow)[v];
        const float e0 = __expf(f.x - mx), e1 = __expf(f.y - mx);
        const float e2 = __expf(f.z - mx), e3 = __expf(f.w - mx);
        sum += (e0 + e1) + (e2 + e3);
        half4 h; h[0] = (_Float16)e0; h[1] = (_Float16)e1; h[2] = (_Float16)e2; h[3] = (_Float16)e3;
        ((half4*)prow)[v] = h;
    }
#pragma unroll
    for (int off = 32; off > 0; off >>= 1) sum += __shfl_down(sum, off);
    if ((tid & 63) == 0) red[tid >> 6] = sum;
    __syncthreads();
    if (tid == 0) inv_l[blockIdx.x] = 1.f / (red[0] + red[1] + red[2] + red[3]);
}

extern "C" void kernel_launch(void* const* d_in, const int* in_sizes, int n_in,
                              void* d_out, int out_size, void* d_ws, size_t ws_size,
                              hipStream_t stream)
{
    const float* E  = (const float*)d_in[0];
    const float* Wq = (const float*)d_in[1];
    const float* bq = (const float*)d_in[2];
    const float* Wk = (const float*)d_in[3];
    const float* bk = (const float*)d_in[4];
    const float* Wv = (const float*)d_in[5];
    const float* bv = (const float*)d_in[6];
    float* out = (float*)d_out;

    char* ws = (char*)d_ws;
    const size_t SZ = (size_t)N_TOK * DIM * sizeof(_Float16);   // 16 MiB
    const size_t WW = (size_t)DIM * DIM * sizeof(_Float16);     // 2 MiB
    _Float16* q_hi = (_Float16*)(ws);
    _Float16* q_lo = (_Float16*)(ws + SZ);
    _Float16* k_hi = (_Float16*)(ws + 2 * SZ);
    _Float16* vt   = (_Float16*)(ws + 3 * SZ);
    float*    invl = (float*)(ws + 4 * SZ);
    char*     scratch = ws + 4 * SZ + 65536;
    _Float16* Ehi = (_Float16*)(scratch);
    _Float16* Elo = (_Float16*)(scratch + SZ);
    _Float16* Wqh = (_Float16*)(scratch + 2 * SZ);
    _Float16* Wkh = (_Float16*)(scratch + 2 * SZ + WW);
    _Float16* Wvh = (_Float16*)(scratch + 2 * SZ + 2 * WW);
    float*    Sc  = (float*)(scratch);
    const size_t esplit_bytes = 2 * SZ + 3 * WW;
    const size_t base = 4 * SZ + 65536;

    int NC = 256;
    const int cands[6] = {8192, 4096, 2048, 1024, 512, 256};
    for (int i = 0; i < 6; i++) {
        size_t sc = (size_t)cands[i] * N_TOK * 4;
        size_t need = base + (sc > esplit_bytes ? sc : esplit_bytes);
        if (ws_size >= need) { NC = cands[i]; break; }
    }

    const dim3 blk(256, 1, 1);
    constexpr int KS = 4;                  // PV split-K factor

    // ---- zero output (PV accumulates atomically) ----
    zero_f32<<<dim3(N_TOK * DIM / 1024, 1, 1), blk, 0, stream>>>(out);

    // ---- pre-split: E -> hi/lo fp16, W -> hi fp16 ----
    split_inputs<<<dim3(DIM * DIM / 1024, 11, 1), blk, 0, stream>>>(
        E, Wq, Wk, Wv, Ehi, Elo, Wqh, Wkh, Wvh);

    // ---- QKV projections (fp16, A 2-term, BK=64, XCD remap) ----
    gemm_f16<128, 64, 64, true, EPI_HILO, true><<<dim3(DIM / 64, N_TOK / 128, 1), blk, 0, stream>>>(
        Ehi, Elo, Wqh, DIM, DIM, DIM, q_hi, DIM, q_lo, bq, nullptr);
    gemm_f16<128, 64, 64, true, EPI_HI, true><<<dim3(DIM / 64, N_TOK / 128, 1), blk, 0, stream>>>(
        Ehi, Elo, Wkh, DIM, DIM, DIM, k_hi, DIM, nullptr, bk, nullptr);
    gemm_f16<128, 64, 64, true, EPI_VT, true><<<dim3(DIM / 64, N_TOK / 128, 1), blk, 0, stream>>>(
        Ehi, Elo, Wvh, DIM, DIM, DIM, vt, N_TOK, nullptr, bv, nullptr);

    // ---- chunked scores -> softmax -> PV ----
    const int nchunks = N_TOK / NC;
    for (int c = 0; c < nchunks; c++) {
        const size_t roff = (size_t)c * NC;
        // S = q_c @ k^T (fp32 into Sc), A split hi+lo, BK=32 (proven config)
        gemm_f16<128, 128, 32, true, EPI_F32, false><<<dim3(N_TOK / 128, NC / 128, 1), blk, 0, stream>>>(
            q_hi + roff * DIM, q_lo + roff * DIM, k_hi, DIM, DIM, DIM,
            Sc, N_TOK, nullptr, nullptr, nullptr);
        // rowwise softmax: P=exp(s-m) fp16 in place, invl=1/sum
        softmax_rows<<<dim3(NC, 1, 1), blk, 0, stream>>>(Sc, invl + roff);
        // out_c += (P @ V) * invl : split-K=4, atomicAdd epilogue, XCD remap
        gemm_f16<128, 64, 64, false, EPI_ATOM, true><<<dim3(DIM / 64, NC / 128, KS), blk, 0, stream>>>(
            (const _Float16*)Sc, nullptr, vt, N_TOK / KS, 2 * N_TOK, N_TOK,
            out + roff * DIM, DIM, nullptr, nullptr, invl + roff);
    }
}

// Round 4
// 784.369 us; speedup vs baseline: 1.2857x; 1.0196x over previous
//
#include <hip/hip_runtime.h>
#include <hip/hip_fp16.h>
#include <cstdint>
#include <cstddef>

typedef _Float16 half8 __attribute__((ext_vector_type(8)));
typedef _Float16 half4 __attribute__((ext_vector_type(4)));
typedef float floatx16 __attribute__((ext_vector_type(16)));

#define N_TOK 8192
#define DIM   1024

// epilogue modes
#define EPI_F32   0   // C fp32 = acc                         (S = q k^T)
#define EPI_HILO  1   // C f16 = hi(acc+bias), C2 f16 = lo    (q)
#define EPI_HI    2   // C f16 = hi(acc+bias)                 (k)
#define EPI_VT    3   // C f16 at [colg*ldc+row] = acc+bias   (v transposed)
#define EPI_ATOM  4   // atomicAdd(C fp32, acc * invl[row])   (out = P V, split-K)

__device__ __forceinline__ void async_tile16(const _Float16* gp, _Float16* lp) {
    __builtin_amdgcn_global_load_lds(
        (const __attribute__((address_space(1))) void*)gp,
        (__attribute__((address_space(3))) void*)lp, 16, 0, 0);
}

// NT GEMM, fp16 inputs, 32x32x16 MFMA core: C[m][n] = sum_k A[m][k]*B[n][k]
// (+ optional lo-term of A). global_load_lds 16B staging, XOR swizzle
// j ^ ((r>>1)&SW) (<=2-way bank aliasing on frag reads = free, m136),
// optional XCD remap, optional split-K over blockIdx.z.
template<int BM, int BN, int BK, bool ASPLIT, int EPI, bool REMAP>
__global__ __launch_bounds__(256)
void gemm_f16(const _Float16* __restrict__ Ahi, const _Float16* __restrict__ Alo,
              const _Float16* __restrict__ B,
              int kslice, int lda, int ldb,
              void* __restrict__ C, int ldc, void* __restrict__ C2,
              const float* __restrict__ bias, const float* __restrict__ invl)
{
    constexpr int MI = BM / 64;           // 2x2 waves, wave tile (BM/2)x(BN/2) of 32x32 MFMA tiles
    constexpr int NI = BN / 64;
    constexpr int CPR = BK / 8;           // 16B chunks per row
    constexpr int SW  = CPR - 1;
    constexpr int RPP = 2048 / BK;        // rows staged per 256-thread pass
    constexpr int IA  = BM * BK / 2048;
    constexpr int IB  = BN * BK / 2048;
    constexpr int A_ELTS = BM * BK;
    constexpr int B_ELTS = BN * BK;
    __shared__ _Float16 smem[(ASPLIT ? 2 : 1) * A_ELTS + B_ELTS];
    constexpr int tAhi = 0;
    constexpr int tAlo = A_ELTS;
    constexpr int tB   = (ASPLIT ? 2 : 1) * A_ELTS;

    int bx = blockIdx.x, by = blockIdx.y, bz = blockIdx.z;
    if constexpr (REMAP) {
        const int gx = gridDim.x, gy = gridDim.y;
        const int gxy = gx * gy;
        const int nb = gxy * gridDim.z;
        const int bid = bz * gxy + by * gx + bx;
        const int nid = (bid & 7) * (nb >> 3) + (bid >> 3);
        bx = nid % gx; by = (nid / gx) % gy; bz = nid / gxy;
    }

    const int tid  = threadIdx.x;
    const int row0 = by * BM;
    const int col0 = bx * BN;
    const int lane = tid & 63;
    const int w    = tid >> 6;
    const int wm   = w & 1, wn = w >> 1;
    const int l31  = lane & 31, lhi = lane >> 5;

    floatx16 acc[MI][NI];
#pragma unroll
    for (int mi = 0; mi < MI; mi++)
#pragma unroll
        for (int ni = 0; ni < NI; ni++)
#pragma unroll
            for (int e = 0; e < 16; e++) acc[mi][ni][e] = 0.f;

    const int r_s = tid / CPR;
    const int j_s = tid % CPR;

    const int k_beg = bz * kslice;
    for (int k0 = k_beg; k0 < k_beg + kslice; k0 += BK) {
        __syncthreads();
#pragma unroll
        for (int i = 0; i < IA; i++) {
            const int r = i * RPP + r_s;
            const int jg = j_s ^ ((r >> 1) & SW);
            async_tile16(Ahi + (size_t)(row0 + r) * lda + k0 + jg * 8,
                         smem + tAhi + (i * 256 + tid) * 8);
            if constexpr (ASPLIT)
                async_tile16(Alo + (size_t)(row0 + r) * lda + k0 + jg * 8,
                             smem + tAlo + (i * 256 + tid) * 8);
        }
#pragma unroll
        for (int i = 0; i < IB; i++) {
            const int r = i * RPP + r_s;
            const int jg = j_s ^ ((r >> 1) & SW);
            async_tile16(B + (size_t)(col0 + r) * ldb + k0 + jg * 8,
                         smem + tB + (i * 256 + tid) * 8);
        }
        __syncthreads();

#pragma unroll
        for (int ks = 0; ks < BK / 16; ks++) {
            half8 af[MI], bf[NI];
            half8 al[ASPLIT ? MI : 1];
            const int cb = ks * 2 + lhi;              // 16B chunk holding k = ks*16 + lhi*8 ...
#pragma unroll
            for (int mi = 0; mi < MI; mi++) {
                const int r = wm * (BM / 2) + mi * 32 + l31;
                const int cj = (cb ^ ((r >> 1) & SW)) * 8;
                af[mi] = *(half8*)&smem[tAhi + r * BK + cj];
                if constexpr (ASPLIT) al[mi] = *(half8*)&smem[tAlo + r * BK + cj];
            }
#pragma unroll
            for (int ni = 0; ni < NI; ni++) {
                const int r = wn * (BN / 2) + ni * 32 + l31;
                const int cj = (cb ^ ((r >> 1) & SW)) * 8;
                bf[ni] = *(half8*)&smem[tB + r * BK + cj];
            }
#pragma unroll
            for (int mi = 0; mi < MI; mi++)
#pragma unroll
                for (int ni = 0; ni < NI; ni++) {
                    acc[mi][ni] = __builtin_amdgcn_mfma_f32_32x32x16_f16(af[mi], bf[ni], acc[mi][ni], 0, 0, 0);
                    if constexpr (ASPLIT)
                        acc[mi][ni] = __builtin_amdgcn_mfma_f32_32x32x16_f16(al[mi], bf[ni], acc[mi][ni], 0, 0, 0);
                }
        }
    }

    // epilogue. 32x32 C/D layout (verified m74/m101): col = lane&31,
    // row = (reg&3) + 8*(reg>>2) + 4*(lane>>5)
#pragma unroll
    for (int mi = 0; mi < MI; mi++) {
#pragma unroll
        for (int ni = 0; ni < NI; ni++) {
            const int colg = col0 + wn * (BN / 2) + ni * 32 + l31;
            const int base = row0 + wm * (BM / 2) + mi * 32 + 4 * lhi;
            float bv = 0.f;
            if constexpr (EPI == EPI_HILO || EPI == EPI_HI || EPI == EPI_VT) bv = bias[colg];
#pragma unroll
            for (int g = 0; g < 4; g++) {
                const int rowb = base + 8 * g;        // rows rowb..rowb+3, regs 4g..4g+3
                if constexpr (EPI == EPI_VT) {
                    half4 hv;
#pragma unroll
                    for (int r2 = 0; r2 < 4; r2++) hv[r2] = (_Float16)(acc[mi][ni][4 * g + r2] + bv);
                    *(half4*)&((_Float16*)C)[(size_t)colg * ldc + rowb] = hv;   // rowb%4==0
                } else {
#pragma unroll
                    for (int r2 = 0; r2 < 4; r2++) {
                        const int rowg = rowb + r2;
                        const float v = acc[mi][ni][4 * g + r2];
                        if constexpr (EPI == EPI_F32) {
                            ((float*)C)[(size_t)rowg * ldc + colg] = v;
                        } else if constexpr (EPI == EPI_ATOM) {
                            atomicAdd(&((float*)C)[(size_t)rowg * ldc + colg], v * invl[rowg]);
                        } else {  // EPI_HILO / EPI_HI
                            const float t = v + bv;
                            const _Float16 hi = (_Float16)t;
                            ((_Float16*)C)[(size_t)rowg * ldc + colg] = hi;
                            if constexpr (EPI == EPI_HILO)
                                ((_Float16*)C2)[(size_t)rowg * ldc + colg] = (_Float16)(t - (float)hi);
                        }
                    }
                }
            }
        }
    }
}

__global__ __launch_bounds__(256)
void zero_f32(float* __restrict__ p)
{
    const size_t i = ((size_t)blockIdx.x * 256 + threadIdx.x) * 4;
    const float4 z = {0.f, 0.f, 0.f, 0.f};
    *(float4*)(p + i) = z;
}

// fp32 -> fp16 hi (+lo) pre-split. grid.y = unit: 0..7 = E chunks, 8/9/10 = Wq/Wk/Wv (hi only).
__global__ __launch_bounds__(256)
void split_inputs(const float* __restrict__ E,
                  const float* __restrict__ Wq, const float* __restrict__ Wk, const float* __restrict__ Wv,
                  _Float16* __restrict__ Ehi, _Float16* __restrict__ Elo,
                  _Float16* __restrict__ Wqh, _Float16* __restrict__ Wkh, _Float16* __restrict__ Wvh)
{
    const int u = blockIdx.y;
    const size_t idx = ((size_t)blockIdx.x * 256 + threadIdx.x) * 4;
    const size_t MM = (size_t)DIM * DIM;
    const float* src; _Float16* dhi; _Float16* dlo = nullptr;
    if (u < 8)      { src = E + u * MM;  dhi = Ehi + u * MM; dlo = Elo + u * MM; }
    else if (u == 8){ src = Wq; dhi = Wqh; }
    else if (u == 9){ src = Wk; dhi = Wkh; }
    else            { src = Wv; dhi = Wvh; }
    const float4 f = *(const float4*)(src + idx);
    half4 hh;
    hh[0] = (_Float16)f.x; hh[1] = (_Float16)f.y; hh[2] = (_Float16)f.z; hh[3] = (_Float16)f.w;
    *(half4*)(dhi + idx) = hh;
    if (u < 8) {
        half4 hl;
        hl[0] = (_Float16)(f.x - (float)hh[0]); hl[1] = (_Float16)(f.y - (float)hh[1]);
        hl[2] = (_Float16)(f.z - (float)hh[2]); hl[3] = (_Float16)(f.w - (float)hh[3]);
        *(half4*)(dlo + idx) = hl;
    }
}

// One block per row: rowmax, P = exp(s-m) fp16 IN PLACE over fp32 row, inv_l = 1/sum.
__global__ __launch_bounds__(256)
void softmax_rows(float* __restrict__ S, float* __restrict__ inv_l)
{
    __shared__ float srow[N_TOK];
    __shared__ float red[4];
    const int tid = threadIdx.x;
    float* row = S + (size_t)blockIdx.x * N_TOK;

    float mx = -3.0e38f;
#pragma unroll
    for (int i = 0; i < 8; i++) {
        const int v = i * 256 + tid;
        const float4 f = ((const float4*)row)[v];
        ((float4*)srow)[v] = f;
        mx = fmaxf(mx, fmaxf(fmaxf(f.x, f.y), fmaxf(f.z, f.w)));
    }
#pragma unroll
    for (int off = 32; off > 0; off >>= 1) mx = fmaxf(mx, __shfl_down(mx, off));
    if ((tid & 63) == 0) red[tid >> 6] = mx;
    __syncthreads();
    mx = fmaxf(fmaxf(red[0], red[1]), fmaxf(red[2], red[3]));
    __syncthreads();

    float sum = 0.f;
    _Float16* prow = (_Float16*)row;
#pragma unroll
    for (int i = 0; i < 8; i++) {
        const int v = i * 256 + tid;
        const float4 f = ((const float4*)srow)[v];
        const float e0 = __expf(f.x - mx), e1 = __expf(f.y - mx);
        const float e2 = __expf(f.z - mx), e3 = __expf(f.w - mx);
        sum += (e0 + e1) + (e2 + e3);
        half4 h; h[0] = (_Float16)e0; h[1] = (_Float16)e1; h[2] = (_Float16)e2; h[3] = (_Float16)e3;
        ((half4*)prow)[v] = h;
    }
#pragma unroll
    for (int off = 32; off > 0; off >>= 1) sum += __shfl_down(sum, off);
    if ((tid & 63) == 0) red[tid >> 6] = sum;
    __syncthreads();
    if (tid == 0) inv_l[blockIdx.x] = 1.f / (red[0] + red[1] + red[2] + red[3]);
}

extern "C" void kernel_launch(void* const* d_in, const int* in_sizes, int n_in,
                              void* d_out, int out_size, void* d_ws, size_t ws_size,
                              hipStream_t stream)
{
    const float* E  = (const float*)d_in[0];
    const float* Wq = (const float*)d_in[1];
    const float* bq = (const float*)d_in[2];
    const float* Wk = (const float*)d_in[3];
    const float* bk = (const float*)d_in[4];
    const float* Wv = (const float*)d_in[5];
    const float* bv = (const float*)d_in[6];
    float* out = (float*)d_out;

    char* ws = (char*)d_ws;
    const size_t SZ = (size_t)N_TOK * DIM * sizeof(_Float16);   // 16 MiB
    const size_t WW = (size_t)DIM * DIM * sizeof(_Float16);     // 2 MiB
    _Float16* q_hi = (_Float16*)(ws);
    _Float16* q_lo = (_Float16*)(ws + SZ);
    _Float16* k_hi = (_Float16*)(ws + 2 * SZ);
    _Float16* vt   = (_Float16*)(ws + 3 * SZ);
    float*    invl = (float*)(ws + 4 * SZ);
    char*     scratch = ws + 4 * SZ + 65536;
    _Float16* Ehi = (_Float16*)(scratch);
    _Float16* Elo = (_Float16*)(scratch + SZ);
    _Float16* Wqh = (_Float16*)(scratch + 2 * SZ);
    _Float16* Wkh = (_Float16*)(scratch + 2 * SZ + WW);
    _Float16* Wvh = (_Float16*)(scratch + 2 * SZ + 2 * WW);
    float*    Sc  = (float*)(scratch);
    const size_t esplit_bytes = 2 * SZ + 3 * WW;
    const size_t base = 4 * SZ + 65536;

    int NC = 256;
    const int cands[6] = {8192, 4096, 2048, 1024, 512, 256};
    for (int i = 0; i < 6; i++) {
        size_t sc = (size_t)cands[i] * N_TOK * 4;
        size_t need = base + (sc > esplit_bytes ? sc : esplit_bytes);
        if (ws_size >= need) { NC = cands[i]; break; }
    }

    const dim3 blk(256, 1, 1);
    constexpr int KS = 4;                  // PV split-K factor

    // ---- zero output (PV accumulates atomically) ----
    zero_f32<<<dim3(N_TOK * DIM / 1024, 1, 1), blk, 0, stream>>>(out);

    // ---- pre-split: E -> hi/lo fp16, W -> hi fp16 ----
    split_inputs<<<dim3(DIM * DIM / 1024, 11, 1), blk, 0, stream>>>(
        E, Wq, Wk, Wv, Ehi, Elo, Wqh, Wkh, Wvh);

    // ---- QKV projections (fp16, A 2-term, BK=64, XCD remap) ----
    gemm_f16<128, 64, 64, true, EPI_HILO, true><<<dim3(DIM / 64, N_TOK / 128, 1), blk, 0, stream>>>(
        Ehi, Elo, Wqh, DIM, DIM, DIM, q_hi, DIM, q_lo, bq, nullptr);
    gemm_f16<128, 64, 64, true, EPI_HI, true><<<dim3(DIM / 64, N_TOK / 128, 1), blk, 0, stream>>>(
        Ehi, Elo, Wkh, DIM, DIM, DIM, k_hi, DIM, nullptr, bk, nullptr);
    gemm_f16<128, 64, 64, true, EPI_VT, true><<<dim3(DIM / 64, N_TOK / 128, 1), blk, 0, stream>>>(
        Ehi, Elo, Wvh, DIM, DIM, DIM, vt, N_TOK, nullptr, bv, nullptr);

    // ---- chunked scores -> softmax -> PV ----
    const int nchunks = N_TOK / NC;
    for (int c = 0; c < nchunks; c++) {
        const size_t roff = (size_t)c * NC;
        // S = q_c @ k^T (fp32 into Sc), A split hi+lo, BK=32
        gemm_f16<128, 128, 32, true, EPI_F32, false><<<dim3(N_TOK / 128, NC / 128, 1), blk, 0, stream>>>(
            q_hi + roff * DIM, q_lo + roff * DIM, k_hi, DIM, DIM, DIM,
            Sc, N_TOK, nullptr, nullptr, nullptr);
        // rowwise softmax: P=exp(s-m) fp16 in place, invl=1/sum
        softmax_rows<<<dim3(NC, 1, 1), blk, 0, stream>>>(Sc, invl + roff);
        // out_c += (P @ V) * invl : split-K=4, atomicAdd epilogue, XCD remap
        gemm_f16<128, 64, 64, false, EPI_ATOM, true><<<dim3(DIM / 64, NC / 128, KS), blk, 0, stream>>>(
            (const _Float16*)Sc, nullptr, vt, N_TOK / KS, 2 * N_TOK, N_TOK,
            out + roff * DIM, DIM, nullptr, nullptr, invl + roff);
    }
}

// Round 5
// 757.739 us; speedup vs baseline: 1.3309x; 1.0351x over previous
//
#include <hip/hip_runtime.h>
#include <hip/hip_fp16.h>
#include <cstdint>
#include <cstddef>

typedef _Float16 half8 __attribute__((ext_vector_type(8)));
typedef _Float16 half4 __attribute__((ext_vector_type(4)));
typedef float floatx16 __attribute__((ext_vector_type(16)));

#define N_TOK 8192
#define DIM   1024

// epilogue modes
#define EPI_F32   0   // C fp32 = acc                         (S = q k^T)
#define EPI_HILO  1   // C f16 = hi(acc+bias), C2 f16 = lo    (q)
#define EPI_HI    2   // C f16 = hi(acc+bias)                 (k)
#define EPI_VT    3   // C f16 at [colg*ldc+row] = acc+bias   (v transposed)
#define EPI_ATOM  4   // atomicAdd(C fp32, acc * invl[row])   (out = P V, split-K)

__device__ __forceinline__ void async_tile16(const _Float16* gp, _Float16* lp) {
    __builtin_amdgcn_global_load_lds(
        (const __attribute__((address_space(1))) void*)gp,
        (__attribute__((address_space(3))) void*)lp, 16, 0, 0);
}

// NT GEMM, fp16 inputs, 32x32x16 MFMA core: C[m][n] = sum_k A[m][k]*B[n][k]
// (+ optional lo-term of A). global_load_lds 16B staging, XOR swizzle
// j ^ ((r>>1)&SW), optional XCD remap, optional split-K over blockIdx.z.
template<int BM, int BN, int BK, bool ASPLIT, int EPI, bool REMAP>
__global__ __launch_bounds__(256)
void gemm_f16(const _Float16* __restrict__ Ahi, const _Float16* __restrict__ Alo,
              const _Float16* __restrict__ B,
              int kslice, int lda, int ldb,
              void* __restrict__ C, int ldc, void* __restrict__ C2,
              const float* __restrict__ bias, const float* __restrict__ invl)
{
    constexpr int MI = BM / 64;           // 2x2 waves, wave tile (BM/2)x(BN/2) of 32x32 MFMA tiles
    constexpr int NI = BN / 64;
    constexpr int CPR = BK / 8;           // 16B chunks per row
    constexpr int SW  = CPR - 1;
    constexpr int RPP = 2048 / BK;        // rows staged per 256-thread pass
    constexpr int IA  = BM * BK / 2048;
    constexpr int IB  = BN * BK / 2048;
    constexpr int A_ELTS = BM * BK;
    constexpr int B_ELTS = BN * BK;
    __shared__ _Float16 smem[(ASPLIT ? 2 : 1) * A_ELTS + B_ELTS];
    constexpr int tAhi = 0;
    constexpr int tAlo = A_ELTS;
    constexpr int tB   = (ASPLIT ? 2 : 1) * A_ELTS;

    int bx = blockIdx.x, by = blockIdx.y, bz = blockIdx.z;
    if constexpr (REMAP) {
        const int gx = gridDim.x, gy = gridDim.y;
        const int gxy = gx * gy;
        const int nb = gxy * gridDim.z;
        const int bid = bz * gxy + by * gx + bx;
        const int nid = (bid & 7) * (nb >> 3) + (bid >> 3);
        bx = nid % gx; by = (nid / gx) % gy; bz = nid / gxy;
    }

    const int tid  = threadIdx.x;
    const int row0 = by * BM;
    const int col0 = bx * BN;
    const int lane = tid & 63;
    const int w    = tid >> 6;
    const int wm   = w & 1, wn = w >> 1;
    const int l31  = lane & 31, lhi = lane >> 5;

    floatx16 acc[MI][NI];
#pragma unroll
    for (int mi = 0; mi < MI; mi++)
#pragma unroll
        for (int ni = 0; ni < NI; ni++)
#pragma unroll
            for (int e = 0; e < 16; e++) acc[mi][ni][e] = 0.f;

    const int r_s = tid / CPR;
    const int j_s = tid % CPR;

    const int k_beg = bz * kslice;
    for (int k0 = k_beg; k0 < k_beg + kslice; k0 += BK) {
        __syncthreads();
#pragma unroll
        for (int i = 0; i < IA; i++) {
            const int r = i * RPP + r_s;
            const int jg = j_s ^ ((r >> 1) & SW);
            async_tile16(Ahi + (size_t)(row0 + r) * lda + k0 + jg * 8,
                         smem + tAhi + (i * 256 + tid) * 8);
            if constexpr (ASPLIT)
                async_tile16(Alo + (size_t)(row0 + r) * lda + k0 + jg * 8,
                             smem + tAlo + (i * 256 + tid) * 8);
        }
#pragma unroll
        for (int i = 0; i < IB; i++) {
            const int r = i * RPP + r_s;
            const int jg = j_s ^ ((r >> 1) & SW);
            async_tile16(B + (size_t)(col0 + r) * ldb + k0 + jg * 8,
                         smem + tB + (i * 256 + tid) * 8);
        }
        __syncthreads();

#pragma unroll
        for (int ks = 0; ks < BK / 16; ks++) {
            half8 af[MI], bf[NI];
            half8 al[ASPLIT ? MI : 1];
            const int cb = ks * 2 + lhi;              // 16B chunk holding k = ks*16 + lhi*8 ...
#pragma unroll
            for (int mi = 0; mi < MI; mi++) {
                const int r = wm * (BM / 2) + mi * 32 + l31;
                const int cj = (cb ^ ((r >> 1) & SW)) * 8;
                af[mi] = *(half8*)&smem[tAhi + r * BK + cj];
                if constexpr (ASPLIT) al[mi] = *(half8*)&smem[tAlo + r * BK + cj];
            }
#pragma unroll
            for (int ni = 0; ni < NI; ni++) {
                const int r = wn * (BN / 2) + ni * 32 + l31;
                const int cj = (cb ^ ((r >> 1) & SW)) * 8;
                bf[ni] = *(half8*)&smem[tB + r * BK + cj];
            }
#pragma unroll
            for (int mi = 0; mi < MI; mi++)
#pragma unroll
                for (int ni = 0; ni < NI; ni++) {
                    acc[mi][ni] = __builtin_amdgcn_mfma_f32_32x32x16_f16(af[mi], bf[ni], acc[mi][ni], 0, 0, 0);
                    if constexpr (ASPLIT)
                        acc[mi][ni] = __builtin_amdgcn_mfma_f32_32x32x16_f16(al[mi], bf[ni], acc[mi][ni], 0, 0, 0);
                }
        }
    }

    // epilogue. 32x32 C/D layout (verified m74/m101): col = lane&31,
    // row = (reg&3) + 8*(reg>>2) + 4*(lane>>5)
#pragma unroll
    for (int mi = 0; mi < MI; mi++) {
#pragma unroll
        for (int ni = 0; ni < NI; ni++) {
            const int colg = col0 + wn * (BN / 2) + ni * 32 + l31;
            const int base = row0 + wm * (BM / 2) + mi * 32 + 4 * lhi;
            float bv = 0.f;
            if constexpr (EPI == EPI_HILO || EPI == EPI_HI || EPI == EPI_VT) bv = bias[colg];
#pragma unroll
            for (int g = 0; g < 4; g++) {
                const int rowb = base + 8 * g;        // rows rowb..rowb+3, regs 4g..4g+3
                if constexpr (EPI == EPI_VT) {
                    half4 hv;
#pragma unroll
                    for (int r2 = 0; r2 < 4; r2++) hv[r2] = (_Float16)(acc[mi][ni][4 * g + r2] + bv);
                    *(half4*)&((_Float16*)C)[(size_t)colg * ldc + rowb] = hv;   // rowb%4==0
                } else {
#pragma unroll
                    for (int r2 = 0; r2 < 4; r2++) {
                        const int rowg = rowb + r2;
                        const float v = acc[mi][ni][4 * g + r2];
                        if constexpr (EPI == EPI_F32) {
                            ((float*)C)[(size_t)rowg * ldc + colg] = v;
                        } else if constexpr (EPI == EPI_ATOM) {
                            atomicAdd(&((float*)C)[(size_t)rowg * ldc + colg], v * invl[rowg]);
                        } else {  // EPI_HILO / EPI_HI
                            const float t = v + bv;
                            const _Float16 hi = (_Float16)t;
                            ((_Float16*)C)[(size_t)rowg * ldc + colg] = hi;
                            if constexpr (EPI == EPI_HILO)
                                ((_Float16*)C2)[(size_t)rowg * ldc + colg] = (_Float16)(t - (float)hi);
                        }
                    }
                }
            }
        }
    }
}

__global__ __launch_bounds__(256)
void zero_f32(float* __restrict__ p)
{
    const size_t i = ((size_t)blockIdx.x * 256 + threadIdx.x) * 4;
    const float4 z = {0.f, 0.f, 0.f, 0.f};
    *(float4*)(p + i) = z;
}

// fp32 -> fp16 hi (+lo) pre-split. grid.y = unit: 0..7 = E chunks, 8/9/10 = Wq/Wk/Wv (hi only).
__global__ __launch_bounds__(256)
void split_inputs(const float* __restrict__ E,
                  const float* __restrict__ Wq, const float* __restrict__ Wk, const float* __restrict__ Wv,
                  _Float16* __restrict__ Ehi, _Float16* __restrict__ Elo,
                  _Float16* __restrict__ Wqh, _Float16* __restrict__ Wkh, _Float16* __restrict__ Wvh)
{
    const int u = blockIdx.y;
    const size_t idx = ((size_t)blockIdx.x * 256 + threadIdx.x) * 4;
    const size_t MM = (size_t)DIM * DIM;
    const float* src; _Float16* dhi; _Float16* dlo = nullptr;
    if (u < 8)      { src = E + u * MM;  dhi = Ehi + u * MM; dlo = Elo + u * MM; }
    else if (u == 8){ src = Wq; dhi = Wqh; }
    else if (u == 9){ src = Wk; dhi = Wkh; }
    else            { src = Wv; dhi = Wvh; }
    const float4 f = *(const float4*)(src + idx);
    half4 hh;
    hh[0] = (_Float16)f.x; hh[1] = (_Float16)f.y; hh[2] = (_Float16)f.z; hh[3] = (_Float16)f.w;
    *(half4*)(dhi + idx) = hh;
    if (u < 8) {
        half4 hl;
        hl[0] = (_Float16)(f.x - (float)hh[0]); hl[1] = (_Float16)(f.y - (float)hh[1]);
        hl[2] = (_Float16)(f.z - (float)hh[2]); hl[3] = (_Float16)(f.w - (float)hh[3]);
        *(half4*)(dlo + idx) = hl;
    }
}

// One block per row: rowmax, P = exp(s-m) fp16 IN PLACE over fp32 row, inv_l = 1/sum.
__global__ __launch_bounds__(256)
void softmax_rows(float* __restrict__ S, float* __restrict__ inv_l)
{
    __shared__ float srow[N_TOK];
    __shared__ float red[4];
    const int tid = threadIdx.x;
    float* row = S + (size_t)blockIdx.x * N_TOK;

    float mx = -3.0e38f;
#pragma unroll
    for (int i = 0; i < 8; i++) {
        const int v = i * 256 + tid;
        const float4 f = ((const float4*)row)[v];
        ((float4*)srow)[v] = f;
        mx = fmaxf(mx, fmaxf(fmaxf(f.x, f.y), fmaxf(f.z, f.w)));
    }
#pragma unroll
    for (int off = 32; off > 0; off >>= 1) mx = fmaxf(mx, __shfl_down(mx, off));
    if ((tid & 63) == 0) red[tid >> 6] = mx;
    __syncthreads();
    mx = fmaxf(fmaxf(red[0], red[1]), fmaxf(red[2], red[3]));
    __syncthreads();

    float sum = 0.f;
    _Float16* prow = (_Float16*)row;
#pragma unroll
    for (int i = 0; i < 8; i++) {
        const int v = i * 256 + tid;
        const float4 f = ((const float4*)srow)[v];
        const float e0 = __expf(f.x - mx), e1 = __expf(f.y - mx);
        const float e2 = __expf(f.z - mx), e3 = __expf(f.w - mx);
        sum += (e0 + e1) + (e2 + e3);
        half4 h; h[0] = (_Float16)e0; h[1] = (_Float16)e1; h[2] = (_Float16)e2; h[3] = (_Float16)e3;
        ((half4*)prow)[v] = h;
    }
#pragma unroll
    for (int off = 32; off > 0; off >>= 1) sum += __shfl_down(sum, off);
    if ((tid & 63) == 0) red[tid >> 6] = sum;
    __syncthreads();
    if (tid == 0) inv_l[blockIdx.x] = 1.f / (red[0] + red[1] + red[2] + red[3]);
}

extern "C" void kernel_launch(void* const* d_in, const int* in_sizes, int n_in,
                              void* d_out, int out_size, void* d_ws, size_t ws_size,
                              hipStream_t stream)
{
    const float* E  = (const float*)d_in[0];
    const float* Wq = (const float*)d_in[1];
    const float* bq = (const float*)d_in[2];
    const float* Wk = (const float*)d_in[3];
    const float* bk = (const float*)d_in[4];
    const float* Wv = (const float*)d_in[5];
    const float* bv = (const float*)d_in[6];
    float* out = (float*)d_out;

    char* ws = (char*)d_ws;
    const size_t SZ = (size_t)N_TOK * DIM * sizeof(_Float16);   // 16 MiB
    const size_t WW = (size_t)DIM * DIM * sizeof(_Float16);     // 2 MiB
    _Float16* q_hi = (_Float16*)(ws);
    _Float16* q_lo = (_Float16*)(ws + SZ);
    _Float16* k_hi = (_Float16*)(ws + 2 * SZ);
    _Float16* vt   = (_Float16*)(ws + 3 * SZ);
    float*    invl = (float*)(ws + 4 * SZ);
    char*     scratch = ws + 4 * SZ + 65536;
    _Float16* Ehi = (_Float16*)(scratch);
    _Float16* Elo = (_Float16*)(scratch + SZ);
    _Float16* Wqh = (_Float16*)(scratch + 2 * SZ);
    _Float16* Wkh = (_Float16*)(scratch + 2 * SZ + WW);
    _Float16* Wvh = (_Float16*)(scratch + 2 * SZ + 2 * WW);
    float*    Sc  = (float*)(scratch);
    const size_t esplit_bytes = 2 * SZ + 3 * WW;
    const size_t base = 4 * SZ + 65536;

    int NC = 256;
    const int cands[6] = {8192, 4096, 2048, 1024, 512, 256};
    for (int i = 0; i < 6; i++) {
        size_t sc = (size_t)cands[i] * N_TOK * 4;
        size_t need = base + (sc > esplit_bytes ? sc : esplit_bytes);
        if (ws_size >= need) { NC = cands[i]; break; }
    }

    const dim3 blk(256, 1, 1);
    constexpr int KS = 4;                  // PV split-K factor

    // ---- zero output (PV accumulates atomically) ----
    zero_f32<<<dim3(N_TOK * DIM / 1024, 1, 1), blk, 0, stream>>>(out);

    // ---- pre-split: E -> hi/lo fp16, W -> hi fp16 ----
    split_inputs<<<dim3(DIM * DIM / 1024, 11, 1), blk, 0, stream>>>(
        E, Wq, Wk, Wv, Ehi, Elo, Wqh, Wkh, Wvh);

    // ---- QKV projections (fp16, BK=64, XCD remap). q,k: E 2-term; v: E hi-only ----
    gemm_f16<128, 64, 64, true, EPI_HILO, true><<<dim3(DIM / 64, N_TOK / 128, 1), blk, 0, stream>>>(
        Ehi, Elo, Wqh, DIM, DIM, DIM, q_hi, DIM, q_lo, bq, nullptr);
    gemm_f16<128, 64, 64, true, EPI_HI, true><<<dim3(DIM / 64, N_TOK / 128, 1), blk, 0, stream>>>(
        Ehi, Elo, Wkh, DIM, DIM, DIM, k_hi, DIM, nullptr, bk, nullptr);
    gemm_f16<128, 64, 64, false, EPI_VT, true><<<dim3(DIM / 64, N_TOK / 128, 1), blk, 0, stream>>>(
        Ehi, nullptr, Wvh, DIM, DIM, DIM, vt, N_TOK, nullptr, bv, nullptr);

    // ---- chunked scores -> softmax -> PV ----
    const int nchunks = N_TOK / NC;
    for (int c = 0; c < nchunks; c++) {
        const size_t roff = (size_t)c * NC;
        // S = q_c @ k^T (fp32 into Sc), A split hi+lo, BK=64 (48KB LDS, 3 blocks/CU)
        gemm_f16<128, 128, 64, true, EPI_F32, false><<<dim3(N_TOK / 128, NC / 128, 1), blk, 0, stream>>>(
            q_hi + roff * DIM, q_lo + roff * DIM, k_hi, DIM, DIM, DIM,
            Sc, N_TOK, nullptr, nullptr, nullptr);
        // rowwise softmax: P=exp(s-m) fp16 in place, invl=1/sum
        softmax_rows<<<dim3(NC, 1, 1), blk, 0, stream>>>(Sc, invl + roff);
        // out_c += (P @ V) * invl : split-K=4, atomicAdd epilogue, XCD remap
        gemm_f16<128, 64, 64, false, EPI_ATOM, true><<<dim3(DIM / 64, NC / 128, KS), blk, 0, stream>>>(
            (const _Float16*)Sc, nullptr, vt, N_TOK / KS, 2 * N_TOK, N_TOK,
            out + roff * DIM, DIM, nullptr, nullptr, invl + roff);
    }
}